// Round 1
// baseline (318.004 us; speedup 1.0000x reference)
//
#include <hip/hip_runtime.h>
#include <hip/hip_bf16.h>
#include <stdint.h>

typedef __attribute__((ext_vector_type(8))) short short8;
typedef __attribute__((ext_vector_type(4))) float floatx4;

// async global->LDS, 16B per lane. LDS dest must be wave-uniform base + lane*16.
#define GLL(gp, lp)                                                                 \
    __builtin_amdgcn_global_load_lds((const __attribute__((address_space(1))) unsigned int*)(gp), \
                                     (__attribute__((address_space(3))) unsigned int*)(lp), 16, 0, 0)

// ---------------------------------------------------------------------------
// Kernel 1: qdq x to MXFP4 (block 32 along K, FLOOR scale), emit bf16.
// One thread = 4 consecutive floats; 8 consecutive lanes = one 32-block.
// ---------------------------------------------------------------------------
__device__ __forceinline__ float qdq1(float xv, float inv, float scale) {
    float a = fabsf(xv) * inv;          // divide by pow2 scale (exact)
    a = fminf(a, 6.0f);
    // RTE onto {0,.5,1,1.5,2,3,4,6}: matches searchsorted+ties-to-even exactly
    float q = (a < 2.0f) ? rintf(a + a) * 0.5f
            : ((a < 4.0f) ? rintf(a) : rintf(a * 0.5f) * 2.0f);
    q *= scale;                         // exact (pow2)
    return copysignf(q, xv);
}

__global__ __launch_bounds__(256) void qdq_x_kernel(const float* __restrict__ x,
                                                    unsigned short* __restrict__ xq,
                                                    int n4) {
    int t = blockIdx.x * 256 + threadIdx.x;
    if (t >= n4) return;
    float4 v = ((const float4*)x)[t];
    float m = fmaxf(fmaxf(fabsf(v.x), fabsf(v.y)), fmaxf(fabsf(v.z), fabsf(v.w)));
    // max over the 8-lane subgroup covering one 32-element MX block
    m = fmaxf(m, __shfl_xor(m, 1, 64));
    m = fmaxf(m, __shfl_xor(m, 2, 64));
    m = fmaxf(m, __shfl_xor(m, 4, 64));

    float scale, inv;
    if (m < 0x1p-123f) {
        // covers max_abs==0 and denormal-ish: ref scale = 2^-126 (q==0 anyway for the tiny cases that matter)
        scale = 0x1p-126f;
        inv = 0x1p126f;
    } else {
        unsigned e = __float_as_uint(m) >> 23;          // exponent field, 4..254 (m normal, finite)
        scale = __uint_as_float((e - 2u) << 23);        // 2^(floor(log2 m) - 2)
        inv = __uint_as_float((256u - e) << 23);        // 2^-(e-129), exact reciprocal
    }

    float r0 = qdq1(v.x, inv, scale);
    float r1 = qdq1(v.y, inv, scale);
    float r2 = qdq1(v.z, inv, scale);
    float r3 = qdq1(v.w, inv, scale);

    // values are exactly representable in bf16 -> truncation is exact
    ushort4 o;
    o.x = (unsigned short)(__float_as_uint(r0) >> 16);
    o.y = (unsigned short)(__float_as_uint(r1) >> 16);
    o.z = (unsigned short)(__float_as_uint(r2) >> 16);
    o.w = (unsigned short)(__float_as_uint(r3) >> 16);
    ((ushort4*)xq)[t] = o;
}

// ---------------------------------------------------------------------------
// Kernel 2: dequant packed fp4 weight (low nibble first) with e8m0 scales -> bf16
// One thread = one packed byte (2 output elements).
// ---------------------------------------------------------------------------
__device__ __forceinline__ float e2m1_mag(int nib) {
    int ee = (nib >> 1) & 3;
    int mm = nib & 1;
    float nrm = __uint_as_float(((126u + (unsigned)ee) << 23) | ((unsigned)mm << 22)); // (1+m/2)*2^(ee-1)
    return (ee == 0) ? (mm ? 0.5f : 0.0f) : nrm;
}

__global__ __launch_bounds__(256) void dequant_w_kernel(const int* __restrict__ wp,
                                                        const int* __restrict__ wsc,
                                                        unsigned int* __restrict__ w,
                                                        int npack) {
    int t = blockIdx.x * 256 + threadIdx.x;
    if (t >= npack) return;
    int p = wp[t];
    int n = t >> 11;        // / 2048 packed per row
    int kp = t & 2047;
    int sc = wsc[n * 128 + (kp >> 4)];
    // e8m0: code c -> 2^(c-127); c==0 -> 2^-127 (fp32 subnormal 0x00400000)
    float s = __uint_as_float(sc ? ((unsigned)sc << 23) : 0x00400000u);

    int lo = p & 0xF;
    int hi = (p >> 4) & 0xF;
    float vlo = e2m1_mag(lo) * s;   // exact (grid * pow2)
    float vhi = e2m1_mag(hi) * s;
    unsigned blo = (__float_as_uint(vlo) ^ ((unsigned)(lo & 8) << 28)) >> 16;
    unsigned bhi = (__float_as_uint(vhi) ^ ((unsigned)(hi & 8) << 28)) & 0xFFFF0000u;
    w[t] = bhi | blo;               // [low, high] interleave, bf16 pair
}

// ---------------------------------------------------------------------------
// Kernel 3: bf16 GEMM, C[M,N] = A[M,K] * B[N,K]^T  (m97 recipe)
// 128x128 tile, 4 waves, each wave 64x64 = 4x4 tiles of 16x16x32 MFMA.
// ---------------------------------------------------------------------------
__global__ __launch_bounds__(256) void gemm_bt_kernel(const unsigned short* __restrict__ A,
                                                      const unsigned short* __restrict__ B,
                                                      float* __restrict__ C,
                                                      int M, int N, int K) {
    __shared__ __align__(16) short sA[128 * 32];
    __shared__ __align__(16) short sB[128 * 32];

    const int tid = threadIdx.x;
    const int bm0 = blockIdx.y << 7;
    const int bn0 = blockIdx.x << 7;
    const int wave = tid >> 6;
    const int lane = tid & 63;
    const int waveM = (wave >> 1) << 6;
    const int waveN = (wave & 1) << 6;
    const int lm = lane & 15;
    const int quad = lane >> 4;

    // staging: slot s (0..511) covers LDS bytes [16s,16s+16) = row s>>2, k-elems (s&3)*8..+8
    const int s1 = tid + 256;
    const short* Ag0 = (const short*)A + (size_t)(bm0 + (tid >> 2)) * K + (tid & 3) * 8;
    const short* Ag1 = (const short*)A + (size_t)(bm0 + (s1 >> 2)) * K + (s1 & 3) * 8;
    const short* Bg0 = (const short*)B + (size_t)(bn0 + (tid >> 2)) * K + (tid & 3) * 8;
    const short* Bg1 = (const short*)B + (size_t)(bn0 + (s1 >> 2)) * K + (s1 & 3) * 8;
    short* lA0 = sA + tid * 8;
    short* lA1 = sA + s1 * 8;
    short* lB0 = sB + tid * 8;
    short* lB1 = sB + s1 * 8;

    floatx4 acc[4][4];
#pragma unroll
    for (int i = 0; i < 4; ++i)
#pragma unroll
        for (int j = 0; j < 4; ++j) acc[i][j] = (floatx4){0.f, 0.f, 0.f, 0.f};

    for (int k0 = 0; k0 < K; k0 += 32) {
        __syncthreads();
        GLL(Ag0 + k0, lA0);
        GLL(Ag1 + k0, lA1);
        GLL(Bg0 + k0, lB0);
        GLL(Bg1 + k0, lB1);
        __syncthreads();   // compiler emits s_waitcnt vmcnt(0) before s_barrier

        short8 af[4], bf[4];
#pragma unroll
        for (int i = 0; i < 4; ++i)
            af[i] = *(const short8*)(sA + (waveM + i * 16 + lm) * 32 + quad * 8);
#pragma unroll
        for (int j = 0; j < 4; ++j)
            bf[j] = *(const short8*)(sB + (waveN + j * 16 + lm) * 32 + quad * 8);
#pragma unroll
        for (int i = 0; i < 4; ++i)
#pragma unroll
            for (int j = 0; j < 4; ++j)
                acc[i][j] = __builtin_amdgcn_mfma_f32_16x16x32_bf16(af[i], bf[j], acc[i][j], 0, 0, 0);
    }

    // C/D layout: col = lane&15, row = quad*4 + reg
#pragma unroll
    for (int i = 0; i < 4; ++i) {
        int row = bm0 + waveM + i * 16 + quad * 4;
#pragma unroll
        for (int j = 0; j < 4; ++j) {
            int col = bn0 + waveN + j * 16 + lm;
            float* cp = C + (size_t)row * N + col;
#pragma unroll
            for (int r = 0; r < 4; ++r)
                cp[(size_t)r * N] = acc[i][j][r];
        }
    }
}

// ---------------------------------------------------------------------------
extern "C" void kernel_launch(void* const* d_in, const int* in_sizes, int n_in,
                              void* d_out, int out_size, void* d_ws, size_t ws_size,
                              hipStream_t stream) {
    const float* x = (const float*)d_in[0];
    const int* wp = (const int*)d_in[1];
    const int* wsc = (const int*)d_in[2];
    float* out = (float*)d_out;

    const int K = 4096;
    const int M = in_sizes[0] / K;           // 4096
    const int N = (in_sizes[1] * 2) / K;     // 4096

    unsigned short* xq = (unsigned short*)d_ws;                        // M*K bf16 = 32 MiB
    unsigned int* wd = (unsigned int*)((char*)d_ws + (size_t)M * K * 2); // N*K bf16 = 32 MiB

    int n4 = (M * K) / 4;
    qdq_x_kernel<<<n4 / 256, 256, 0, stream>>>(x, xq, n4);

    int npack = (N * K) / 2;
    dequant_w_kernel<<<npack / 256, 256, 0, stream>>>(wp, wsc, wd, npack);

    dim3 grid(N / 128, M / 128);
    gemm_bt_kernel<<<grid, 256, 0, stream>>>(xq, (const unsigned short*)wd, out, M, N, K);
}

// Round 3
// 203.989 us; speedup vs baseline: 1.5589x; 1.5589x over previous
//
#include <hip/hip_runtime.h>
#include <stdint.h>

typedef __attribute__((ext_vector_type(4)))  int   intx4;
typedef __attribute__((ext_vector_type(8)))  int   intx8;
typedef __attribute__((ext_vector_type(16))) float floatx16;

#define GLL16(gp, lp)                                                               \
    __builtin_amdgcn_global_load_lds((const __attribute__((address_space(1))) unsigned int*)(gp), \
                                     (__attribute__((address_space(3))) unsigned int*)(lp), 16, 0, 0)
#define GLL4(gp, lp)                                                                \
    __builtin_amdgcn_global_load_lds((const __attribute__((address_space(1))) unsigned int*)(gp), \
                                     (__attribute__((address_space(3))) unsigned int*)(lp), 4, 0, 0)

// ---------------------------------------------------------------------------
// Kernel 1: quantize x (fp32) -> packed e2m1 nibbles (low nibble = lower k) +
// e8m0 scale codes, transposed layout xs_t[kb][M] for coalesced GEMM staging.
// One thread = one 32-element MX block.
// ---------------------------------------------------------------------------
__device__ __forceinline__ uint32_t enc1(float xv, float inv) {
    float a = fminf(fabsf(xv) * inv, 6.0f);
    // RTE onto e2m1 grid {0,.5,1,1.5,2,3,4,6} -> code 0..7 (matches ref ties-to-even)
    int e;
    if (a < 2.0f)      e = (int)rintf(a + a);          // 0,.5,1,1.5,2 -> 0..4
    else if (a < 4.0f) e = (int)rintf(a) + 2;          // 2,3,4        -> 4..6
    else               e = (int)rintf(a * 0.5f) + 4;   // 4,6          -> 6,7
    return (uint32_t)e | ((__float_as_uint(xv) >> 28) & 8u);   // sign -> bit 3
}

__global__ __launch_bounds__(256) void quant_x_kernel(const float* __restrict__ x,
                                                      uint32_t* __restrict__ xq,
                                                      uint8_t* __restrict__ xs_t,
                                                      int M, int K) {
    int t = blockIdx.x * 256 + threadIdx.x;     // t < M * (K/32)
    int kbpr = K >> 5;                          // blocks per row (128)
    int m = t / kbpr;
    int kb = t - m * kbpr;
    const float4* src = (const float4*)(x + (size_t)m * K + (size_t)kb * 32);
    float4 v[8];
#pragma unroll
    for (int i = 0; i < 8; ++i) v[i] = src[i];
    float mx = 0.f;
#pragma unroll
    for (int i = 0; i < 8; ++i)
        mx = fmaxf(mx, fmaxf(fmaxf(fabsf(v[i].x), fabsf(v[i].y)),
                             fmaxf(fabsf(v[i].z), fabsf(v[i].w))));
    // FLOOR scale: e8m0 code = exp_field(max) - 2, clamped so scale >= 2^-126
    unsigned ef = __float_as_uint(mx) >> 23;
    unsigned code = (ef < 3u) ? 1u : (ef - 2u);
    float inv = __uint_as_float((254u - code) << 23);   // exact 2^(127-code)

    uint32_t w[4];
#pragma unroll
    for (int d = 0; d < 4; ++d) {
        float4 va = v[2 * d], vb = v[2 * d + 1];
        w[d] =  enc1(va.x, inv)        | (enc1(va.y, inv) << 4)
             | (enc1(va.z, inv) << 8)  | (enc1(va.w, inv) << 12)
             | (enc1(vb.x, inv) << 16) | (enc1(vb.y, inv) << 20)
             | (enc1(vb.z, inv) << 24) | (enc1(vb.w, inv) << 28);
    }
    ((uint4*)xq)[t] = make_uint4(w[0], w[1], w[2], w[3]);
    xs_t[(size_t)kb * M + m] = (uint8_t)code;
}

// ---------------------------------------------------------------------------
// Kernel 2: transpose weight scales int32[N][K/32] -> uint8[K/32][N]
// ---------------------------------------------------------------------------
__global__ __launch_bounds__(256) void tscale_kernel(const int* __restrict__ wsc,
                                                     uint8_t* __restrict__ ws_t,
                                                     int N, int kbpr) {
    int t = blockIdx.x * 256 + threadIdx.x;     // t < N * kbpr
    int n = t / kbpr;
    int kb = t - n * kbpr;
    ws_t[(size_t)kb * N + n] = (uint8_t)wsc[t];
}

// ---------------------------------------------------------------------------
// Kernel 2b: repack weight. setup stores ONE packed byte per int32 (0..255).
// Densify to a true uint8 nibble array: wrep[i] = (uint8)wp[i].
// Each thread handles 4 ints -> writes one uint32.
// ---------------------------------------------------------------------------
__global__ __launch_bounds__(256) void repack_w_kernel(const int* __restrict__ wp,
                                                       uint32_t* __restrict__ wrep,
                                                       int n4) {
    int t = blockIdx.x * 256 + threadIdx.x;     // t < npack/4
    if (t >= n4) return;
    int4 p = ((const int4*)wp)[t];
    wrep[t] = (uint32_t)(p.x & 0xFF) | ((uint32_t)(p.y & 0xFF) << 8)
            | ((uint32_t)(p.z & 0xFF) << 16) | ((uint32_t)(p.w & 0xFF) << 24);
}

// ---------------------------------------------------------------------------
// Kernel 3: MXFP4 GEMM. C[M,N] = sum_k (A_fp4*2^sa)(B_fp4*2^sb), B is N-major
// (weight rows), K-major packed nibbles. 128x128 tile, BK=128 (64 B packed),
// 4 waves x (2x2) v_mfma_scale_f32_32x32x64_f8f6f4 (fmt 4 = fp4 e2m1).
// Per-lane fragment: row = lane&31, k = (lane>>5)*32 + i  (one MX block) ->
// per-lane scale byte = that block's e8m0 code.
// XOR swizzle on the 16B piece index breaks stride-64 LDS bank aliasing.
// ---------------------------------------------------------------------------
__global__ __launch_bounds__(256) void gemm_mx_kernel(const uint8_t* __restrict__ Apk,
                                                      const uint8_t* __restrict__ Bpk,
                                                      const uint8_t* __restrict__ AsT,
                                                      const uint8_t* __restrict__ BsT,
                                                      float* __restrict__ C,
                                                      int M, int N, int K) {
    __shared__ __align__(16) uint8_t sA[8192];    // 128 rows x 64 B
    __shared__ __align__(16) uint8_t sB[8192];
    __shared__ __align__(16) uint8_t sAs[512];    // [kbslice 0..3][row 0..127]
    __shared__ __align__(16) uint8_t sBs[512];

    const int tid = threadIdx.x;
    const int bm0 = blockIdx.y << 7;
    const int bn0 = blockIdx.x << 7;
    const int wave = tid >> 6;
    const int lane = tid & 63;
    const int wm = (wave >> 1) << 6;
    const int wn = (wave & 1) << 6;
    const int row = lane & 31;
    const int h = lane >> 5;
    const int Kb = K >> 1;                        // packed bytes per row

    // data staging: slot s covers LDS [16s,16s+16); content = row s>>2,
    // piece p = (s&3) ^ (row&3)  (XOR swizzle, involution)
    const int s0 = tid, s1 = tid + 256;
    const int r0 = s0 >> 2, p0 = (s0 & 3) ^ (r0 & 3);
    const int r1 = s1 >> 2, p1 = (s1 & 3) ^ (r1 & 3);
    const uint8_t* Ag0 = Apk + (size_t)(bm0 + r0) * Kb + p0 * 16;
    const uint8_t* Ag1 = Apk + (size_t)(bm0 + r1) * Kb + p1 * 16;
    const uint8_t* Bg0 = Bpk + (size_t)(bn0 + r0) * Kb + p0 * 16;
    const uint8_t* Bg1 = Bpk + (size_t)(bn0 + r1) * Kb + p1 * 16;

    // scale staging: waves 0-1 stage A scales, waves 2-3 stage B scales
    const int st = tid & 127;
    const int sj = st >> 5, si = st & 31;
    const uint8_t* Sg = (tid < 128) ? (AsT + (size_t)sj * M + bm0 + si * 4)
                                    : (BsT + (size_t)sj * N + bn0 + si * 4);
    uint8_t* Sl = (tid < 128) ? (sAs + st * 4) : (sBs + st * 4);
    const size_t sAdv = (size_t)4 * (size_t)((tid < 128) ? M : N);

    floatx16 acc[2][2];
#pragma unroll
    for (int a = 0; a < 2; ++a)
#pragma unroll
        for (int b = 0; b < 2; ++b)
#pragma unroll
            for (int r = 0; r < 16; ++r) acc[a][b][r] = 0.f;

    const int nchunk = K >> 7;                    // 32
    for (int c = 0; c < nchunk; ++c) {
        __syncthreads();
        const size_t koff = (size_t)c << 6;       // 64 B per chunk
        GLL16(Ag0 + koff, sA + s0 * 16);
        GLL16(Ag1 + koff, sA + s1 * 16);
        GLL16(Bg0 + koff, sB + s0 * 16);
        GLL16(Bg1 + koff, sB + s1 * 16);
        GLL4(Sg + (size_t)c * sAdv, Sl);
        __syncthreads();

#pragma unroll
        for (int s = 0; s < 2; ++s) {
            intx4 a4[2], b4[2];
            int sa[2], sb[2];
            const int kp = 2 * s + h;             // 16B piece index 0..3
#pragma unroll
            for (int mt = 0; mt < 2; ++mt) {
                const int lr = wm + mt * 32 + row;
                a4[mt] = *(const intx4*)(sA + lr * 64 + ((kp ^ (lr & 3)) << 4));
                sa[mt] = sAs[kp * 128 + lr];
            }
#pragma unroll
            for (int nt = 0; nt < 2; ++nt) {
                const int lr = wn + nt * 32 + row;
                b4[nt] = *(const intx4*)(sB + lr * 64 + ((kp ^ (lr & 3)) << 4));
                sb[nt] = sBs[kp * 128 + lr];
            }
#pragma unroll
            for (int mt = 0; mt < 2; ++mt)
#pragma unroll
                for (int nt = 0; nt < 2; ++nt) {
                    intx8 a8 = {a4[mt][0], a4[mt][1], a4[mt][2], a4[mt][3], 0, 0, 0, 0};
                    intx8 b8 = {b4[nt][0], b4[nt][1], b4[nt][2], b4[nt][3], 0, 0, 0, 0};
                    acc[mt][nt] = __builtin_amdgcn_mfma_scale_f32_32x32x64_f8f6f4(
                        a8, b8, acc[mt][nt], 4, 4, 0, sa[mt], 0, sb[nt]);
                }
        }
    }

    // C/D layout (32x32): col = lane&31, row = (reg&3) + 8*(reg>>2) + 4*(lane>>5)
#pragma unroll
    for (int mt = 0; mt < 2; ++mt)
#pragma unroll
        for (int nt = 0; nt < 2; ++nt) {
            const int col = bn0 + wn + nt * 32 + row;
#pragma unroll
            for (int g = 0; g < 4; ++g) {
                const int rw = bm0 + wm + mt * 32 + 8 * g + 4 * h;
#pragma unroll
                for (int q = 0; q < 4; ++q)
                    C[(size_t)(rw + q) * N + col] = acc[mt][nt][4 * g + q];
            }
        }
}

// ---------------------------------------------------------------------------
extern "C" void kernel_launch(void* const* d_in, const int* in_sizes, int n_in,
                              void* d_out, int out_size, void* d_ws, size_t ws_size,
                              hipStream_t stream) {
    const float* x = (const float*)d_in[0];
    const int* wp = (const int*)d_in[1];
    const int* wsc = (const int*)d_in[2];
    float* out = (float*)d_out;

    const int K = 4096;
    const int M = in_sizes[0] / K;            // 4096
    const int N = (in_sizes[1] * 2) / K;      // 4096
    const int kbpr = K / 32;                  // 128
    const int npack = N * K / 2;              // weight packed bytes

    uint32_t* xq   = (uint32_t*)d_ws;                                  // 8 MiB
    uint8_t*  xs   = (uint8_t*)d_ws + (size_t)M * K / 2;               // 512 KiB
    uint8_t*  wst  = xs + (size_t)M * kbpr;                            // 512 KiB
    uint32_t* wrep = (uint32_t*)(wst + (size_t)N * kbpr);              // 8 MiB

    quant_x_kernel<<<(M * kbpr) / 256, 256, 0, stream>>>(x, xq, xs, M, K);
    tscale_kernel<<<(N * kbpr) / 256, 256, 0, stream>>>(wsc, wst, N, kbpr);
    repack_w_kernel<<<(npack / 4 + 255) / 256, 256, 0, stream>>>(wp, wrep, npack / 4);

    dim3 grid(N / 128, M / 128);
    gemm_mx_kernel<<<grid, 256, 0, stream>>>((const uint8_t*)xq, (const uint8_t*)wrep,
                                             xs, wst, out, M, N, K);
}